// Round 8
// baseline (75.486 us; speedup 1.0000x reference)
//
#include <hip/hip_runtime.h>

// out[b] = sum_g exp(-(||x_b||^2+||c_g||^2-2 x_b.c_g)/2) * w[g]
// B=16384, G=8192, D=64 fp32.
// v8: split-bf16 3-pass MFMA. R7 post-mortem: compiler sinks register
// prefetches (VGPR 92 vs planned 212) -> use global_load_lds into
// WAVE-PRIVATE LDS double buffers: no VGPR cost (nothing to sink), issue
// order preserved, depth enforced by counted s_waitcnt vmcnt(8) (T4).
// No barriers in the loop (LDS buffers are per-wave; only cw table is
// block-shared, one prologue barrier). Loop VMEM = exactly 8 gl_lds/iter
// (cw read from LDS) so the vmcnt count is exact.
// 4 waves x 64 rows/block, gp=b&7 col part, 32 tiles of 32 cols.
// LDS 72KB -> 2 blocks/CU; grid 512 = exactly one round.

typedef __attribute__((ext_vector_type(8))) short short8v;
typedef __attribute__((ext_vector_type(16))) float f32x16;
typedef unsigned short u16;
typedef unsigned int u32;

#define L2E   1.4426950408889634f
#define NHL2E 0.72134752044448170f   // log2(e)/2
#define GSPLIT 8                     // 1024 cols per wave sweep

__device__ __forceinline__ u16 f2bf(float x){
  u32 u = __float_as_uint(x);
  return (u16)((u + 0x7FFFu + ((u >> 16) & 1u)) >> 16);   // RNE
}
__device__ __forceinline__ float bf2f(u16 h){ return __uint_as_float(((u32)h) << 16); }

__device__ __forceinline__ void gl_lds16(const void* g, void* l){
  __builtin_amdgcn_global_load_lds((const __attribute__((address_space(1))) u32*)g,
                                   (__attribute__((address_space(3))) u32*)l, 16, 0, 0);
}

#define MFMA(a,b,c) __builtin_amdgcn_mfma_f32_32x32x16_bf16(a,b,c,0,0,0)

// ---- one-time: C [G][64] fp32 -> hi/lo bf16 in fragment order + (cn,w) ----
// frag unit (cg=g/32, f): byte base = cg*4096 + f*1024 + l*16
__global__ __launch_bounds__(256)
void convert_C(const float* __restrict__ C, const float* __restrict__ W,
               u16* __restrict__ Chi, u16* __restrict__ Clo,
               float2* __restrict__ cw, int G){
  int idx = blockIdx.x*256 + threadIdx.x;
  int g = idx >> 2, f = idx & 3;
  if (g >= G) return;
  const float* row = C + (size_t)g*64 + f*16;
  int cg = g >> 5, cl = g & 31;
  float norm = 0.f;
  u16 hb[16], lb[16];
  #pragma unroll
  for (int q=0; q<4; q++){
    float4 v = *(const float4*)(row + q*4);
    float xv[4] = {v.x, v.y, v.z, v.w};
    #pragma unroll
    for (int e=0; e<4; e++){
      float x = xv[e];
      norm = fmaf(x, x, norm);
      u16 hh = f2bf(x); hb[q*4+e] = hh;
      lb[q*4+e] = f2bf(x - bf2f(hh));
    }
  }
  norm += __shfl_xor(norm, 1);
  norm += __shfl_xor(norm, 2);
  size_t u = ((size_t)(cg*4 + f)*64 + cl)*8;
  *(short8v*)(Chi + u)        = *(short8v*)hb;        // h=0 (k 0..7)
  *(short8v*)(Chi + u + 256)  = *(short8v*)(hb + 8);  // h=1 (k 8..15)
  *(short8v*)(Clo + u)        = *(short8v*)lb;
  *(short8v*)(Clo + u + 256)  = *(short8v*)(lb + 8);
  if (f == 0) cw[g] = make_float2(-NHL2E*norm, W[g]);
}

__global__ __launch_bounds__(256, 2)
void rbf_mfma(const float* __restrict__ X, const u16* __restrict__ Chi,
              const u16* __restrict__ Clo, const float2* __restrict__ cw,
              float* __restrict__ out){
  // [wave][dbuf][frag 0..3=Chi f, 4..7=Clo f][lane] : 64 KB
  __shared__ short8v Bbuf[4][2][8][64];
  __shared__ float2 cwsh[1024];          // this gp's (cn,w), 8 KB

  const int tid = threadIdx.x;
  const int l  = tid & 63;
  const int cl = l & 31;
  const int h  = l >> 5;
  const int w  = tid >> 6;
  const int b  = blockIdx.x;
  const int gp = b & 7;
  const int rows0 = ((b >> 3)*4 + w) * 64;

  // ---- A: 64 rows (2 rowfrags) hi/lo bf16 in registers ----
  short8v ah[2][4], al[2][4];
  float xn[2];
  #pragma unroll
  for (int rf=0; rf<2; rf++){
    const float* xr = X + (size_t)(rows0 + rf*32 + cl)*64;
    float s = 0.f;
    #pragma unroll
    for (int f=0; f<4; f++){
      float4 v0 = *(const float4*)(xr + f*16 + h*8);
      float4 v1 = *(const float4*)(xr + f*16 + h*8 + 4);
      float xv[8] = {v0.x,v0.y,v0.z,v0.w,v1.x,v1.y,v1.z,v1.w};
      u16 hb[8], lb[8];
      #pragma unroll
      for (int e=0;e<8;e++){
        float x = xv[e];
        s = fmaf(x, x, s);
        u16 hh = f2bf(x); hb[e]=hh;
        lb[e] = f2bf(x - bf2f(hh));
      }
      ah[rf][f] = *(short8v*)hb;
      al[rf][f] = *(short8v*)lb;
    }
    s += __shfl_xor(s, 32);
    xn[rf] = -NHL2E * s;
  }

  const char* gH = (const char*)Chi + (size_t)gp*131072;
  const char* gL = (const char*)Clo + (size_t)gp*131072;

  // stage tile T (8x 1KB frags) into wave-private buf DB; src has per-lane
  // l*16, dest is wave-uniform (HW adds lane*16).
  #define STAGE(T, DB) do {                                   \
    const size_t o_ = (size_t)(T)*4096 + (size_t)l*16;        \
    char* d_ = (char*)(&Bbuf[w][DB][0][0]);                   \
    gl_lds16(gH + o_,        d_);                             \
    gl_lds16(gH + o_ + 1024, d_ + 1024);                      \
    gl_lds16(gH + o_ + 2048, d_ + 2048);                      \
    gl_lds16(gH + o_ + 3072, d_ + 3072);                      \
    gl_lds16(gL + o_,        d_ + 4096);                      \
    gl_lds16(gL + o_ + 1024, d_ + 5120);                      \
    gl_lds16(gL + o_ + 2048, d_ + 6144);                      \
    gl_lds16(gL + o_ + 3072, d_ + 7168);                      \
  } while(0)

  // ---- prologue: cw table (2 rounds) + tile 0; drain once; one barrier ----
  {
    const char* cwg = (const char*)(cw + gp*1024);
    gl_lds16(cwg + (size_t)tid*16,        (char*)cwsh + w*1024);
    gl_lds16(cwg + 4096 + (size_t)tid*16, (char*)cwsh + 4096 + w*1024);
  }
  STAGE(0, 0);
  asm volatile("s_waitcnt vmcnt(0)" ::: "memory");
  __syncthreads();   // cwsh written by all waves; B bufs are private

  float racc0[16], racc1[16];
  #pragma unroll
  for (int r=0;r<16;r++){ racc0[r]=0.f; racc1[r]=0.f; }

  int cur = 0;
  #pragma unroll 1
  for (int t = 0; t < 32; ++t){
    STAGE((t+1)&31, cur^1);                       // depth-1 tile prefetch
    asm volatile("s_waitcnt vmcnt(8)" ::: "memory");  // tile t landed
    __builtin_amdgcn_sched_barrier(0);

    const short8v* bb = &Bbuf[w][cur][0][0];
    const float2 cwv = cwsh[t*32 + cl];

    f32x16 a0 = {}, a1 = {};
    __builtin_amdgcn_s_setprio(1);
    #pragma unroll
    for (int f=0; f<4; ++f){
      short8v bh = bb[f*64 + l];
      short8v bl = bb[(4+f)*64 + l];
      a0 = MFMA(ah[0][f], bh, a0);
      a1 = MFMA(ah[1][f], bh, a1);
      a0 = MFMA(ah[0][f], bl, a0);
      a1 = MFMA(ah[1][f], bl, a1);
      a0 = MFMA(al[0][f], bh, a0);
      a1 = MFMA(al[1][f], bh, a1);
    }
    __builtin_amdgcn_s_setprio(0);

    #pragma unroll
    for (int r=0;r<16;++r){
      racc0[r] = fmaf(__builtin_amdgcn_exp2f(fmaf(a0[r], L2E, cwv.x)), cwv.y, racc0[r]);
      racc1[r] = fmaf(__builtin_amdgcn_exp2f(fmaf(a1[r], L2E, cwv.x)), cwv.y, racc1[r]);
    }
    cur ^= 1;
  }
  #undef STAGE
  asm volatile("s_waitcnt vmcnt(0)" ::: "memory");  // drain stray prefetch

  // ---- reduce over 32 col-lanes, fold 2^xn, one atomic per row ----
  #pragma unroll
  for (int rf=0; rf<2; rf++){
    #pragma unroll
    for (int r=0;r<16;r++){
      float v = rf ? racc1[r] : racc0[r];
      v += __shfl_xor(v, 1);
      v += __shfl_xor(v, 2);
      v += __shfl_xor(v, 4);
      v += __shfl_xor(v, 8);
      v += __shfl_xor(v, 16);
      const int rit = (r&3) + 8*(r>>2) + 4*h;
      const float xnv = __shfl(xn[rf], rit);
      if (cl == 0)
        atomicAdd(&out[rows0 + rf*32 + rit], v * __builtin_amdgcn_exp2f(xnv));
    }
  }
}

extern "C" void kernel_launch(void* const* d_in, const int* in_sizes, int n_in,
                              void* d_out, int out_size, void* d_ws, size_t ws_size,
                              hipStream_t stream) {
  const float* X = (const float*)d_in[0];   // [B,64]
  const float* C = (const float*)d_in[1];   // [G,64]
  const float* W = (const float*)d_in[2];   // [G]
  float* out = (float*)d_out;               // [B]
  const int B = in_sizes[0] / 64;
  const int G = in_sizes[2];

  u16* Chi = (u16*)d_ws;                         // 1 MB
  u16* Clo = Chi + (size_t)G*64;                 // 1 MB
  float2* cw = (float2*)(Clo + (size_t)G*64);    // 64 KB

  hipMemsetAsync(out, 0, (size_t)B*sizeof(float), stream);
  convert_C<<<(G*4)/256, 256, 0, stream>>>(C, W, Chi, Clo, cw, G);
  rbf_mfma<<<(B/256)*GSPLIT, 256, 0, stream>>>(X, Chi, Clo, cw, out);
}

// Round 9
// 74.591 us; speedup vs baseline: 1.0120x; 1.0120x over previous
//
#include <hip/hip_runtime.h>

// out[b] = sum_g exp(-(||x_b||^2+||c_g||^2-2 x_b.c_g)/2) * w[g]
// B=16384, G=8192, D=64 fp32.
// v9: split-bf16 3-pass MFMA. R8 post-mortem: epilogue (exp2+fma) cost ~=
// MFMA cost on disjoint pipes, but 2 lockstep waves/SIMD never overlap them;
// also R8 staged 4 identical private B copies. Now: block-shared B double
// buffer (16KB, cooperative 2 gl_lds/wave/tile), one __syncthreads per tile
// (drain is free: prefetch spans full tile), GP=12 -> grid 768 = 3 blocks/CU,
// 3 waves/SIMD from DIFFERENT blocks -> anti-phase MFMA/epilogue overlap.

typedef __attribute__((ext_vector_type(8))) short short8v;
typedef __attribute__((ext_vector_type(16))) float f32x16;
typedef unsigned short u16;
typedef unsigned int u32;

#define L2E   1.4426950408889634f
#define NHL2E 0.72134752044448170f   // log2(e)/2
#define GP 12                        // col parts: 0..3 -> 22 tiles, 4..11 -> 21

__device__ __forceinline__ u16 f2bf(float x){
  u32 u = __float_as_uint(x);
  return (u16)((u + 0x7FFFu + ((u >> 16) & 1u)) >> 16);   // RNE
}
__device__ __forceinline__ float bf2f(u16 h){ return __uint_as_float(((u32)h) << 16); }

__device__ __forceinline__ void gl_lds16(const void* g, void* l){
  __builtin_amdgcn_global_load_lds((const __attribute__((address_space(1))) u32*)g,
                                   (__attribute__((address_space(3))) u32*)l, 16, 0, 0);
}

#define MFMA(a,b,c) __builtin_amdgcn_mfma_f32_32x32x16_bf16(a,b,c,0,0,0)

// ---- one-time: C [G][64] fp32 -> hi/lo bf16 in fragment order + (cn,w) ----
// frag unit (cg=g/32, f): byte base = cg*4096 + f*1024 + l*16
__global__ __launch_bounds__(256)
void convert_C(const float* __restrict__ C, const float* __restrict__ W,
               u16* __restrict__ Chi, u16* __restrict__ Clo,
               float2* __restrict__ cw, int G){
  int idx = blockIdx.x*256 + threadIdx.x;
  int g = idx >> 2, f = idx & 3;
  if (g >= G) return;
  const float* row = C + (size_t)g*64 + f*16;
  int cg = g >> 5, cl = g & 31;
  float norm = 0.f;
  u16 hb[16], lb[16];
  #pragma unroll
  for (int q=0; q<4; q++){
    float4 v = *(const float4*)(row + q*4);
    float xv[4] = {v.x, v.y, v.z, v.w};
    #pragma unroll
    for (int e=0; e<4; e++){
      float x = xv[e];
      norm = fmaf(x, x, norm);
      u16 hh = f2bf(x); hb[q*4+e] = hh;
      lb[q*4+e] = f2bf(x - bf2f(hh));
    }
  }
  norm += __shfl_xor(norm, 1);
  norm += __shfl_xor(norm, 2);
  size_t u = ((size_t)(cg*4 + f)*64 + cl)*8;
  *(short8v*)(Chi + u)        = *(short8v*)hb;        // h=0 (k 0..7)
  *(short8v*)(Chi + u + 256)  = *(short8v*)(hb + 8);  // h=1 (k 8..15)
  *(short8v*)(Clo + u)        = *(short8v*)lb;
  *(short8v*)(Clo + u + 256)  = *(short8v*)(lb + 8);
  if (f == 0) cw[g] = make_float2(-NHL2E*norm, W[g]);
}

__global__ __launch_bounds__(256, 3)
void rbf_mfma(const float* __restrict__ X, const u16* __restrict__ Chi,
              const u16* __restrict__ Clo, const float2* __restrict__ cw,
              float* __restrict__ out){
  __shared__ short8v Bbuf[2][8][64];   // [dbuf][frag 0..3=Chi f,4..7=Clo f][lane] 16KB
  __shared__ float2 cwsh[704];         // (cn,w) for this part, <=5.6 KB

  const int tid = threadIdx.x;
  const int l  = tid & 63;
  const int cl = l & 31;
  const int h  = l >> 5;
  const int w  = tid >> 6;
  const int b  = blockIdx.x;
  const int gp = b % GP;
  const int rows0 = (b / GP) * 256 + w * 64;
  const int t0  = gp * 21 + (gp < 4 ? gp : 4);     // global col-tile base
  const int ntl = (gp < 4) ? 22 : 21;              // tiles in this part

  // ---- A: 64 rows (2 rowfrags) hi/lo bf16 in registers ----
  short8v ah[2][4], al[2][4];
  float xn[2];
  #pragma unroll
  for (int rf=0; rf<2; rf++){
    const float* xr = X + (size_t)(rows0 + rf*32 + cl)*64;
    float s = 0.f;
    #pragma unroll
    for (int f=0; f<4; f++){
      float4 v0 = *(const float4*)(xr + f*16 + h*8);
      float4 v1 = *(const float4*)(xr + f*16 + h*8 + 4);
      float xv[8] = {v0.x,v0.y,v0.z,v0.w,v1.x,v1.y,v1.z,v1.w};
      u16 hb[8], lb[8];
      #pragma unroll
      for (int e=0;e<8;e++){
        float x = xv[e];
        s = fmaf(x, x, s);
        u16 hh = f2bf(x); hb[e]=hh;
        lb[e] = f2bf(x - bf2f(hh));
      }
      ah[rf][f] = *(short8v*)hb;
      al[rf][f] = *(short8v*)lb;
    }
    s += __shfl_xor(s, 32);
    xn[rf] = -NHL2E * s;
  }

  const char* gH = (const char*)Chi;
  const char* gL = (const char*)Clo;

  // cooperative stage of tile T (8x1KB frags): wave w owns frags 2w,2w+1.
  // w=0,1 -> Chi f0..3 ; w=2,3 -> Clo f0..3. LDS dest wave-uniform (+lane*16).
  #define STAGE(T, DB) do {                                        \
    const size_t o_ = (size_t)(T)*4096 + (size_t)l*16;             \
    const char* s_ = (w < 2 ? gH : gL) + o_ + (size_t)(w & 1)*2048;\
    char* d_ = (char*)(&Bbuf[DB][0][0]) + (size_t)w*2048;          \
    gl_lds16(s_,        d_);                                       \
    gl_lds16(s_ + 1024, d_ + 1024);                                \
  } while(0)

  // ---- prologue: cw table -> LDS; stage tile 0; drain; barrier ----
  for (int i = tid; i < ntl*32; i += 256) cwsh[i] = cw[t0*32 + i];
  STAGE(t0, 0);
  asm volatile("s_waitcnt vmcnt(0)" ::: "memory");
  __syncthreads();

  float racc0[16], racc1[16];
  #pragma unroll
  for (int r=0;r<16;r++){ racc0[r]=0.f; racc1[r]=0.f; }

  int cur = 0;
  #pragma unroll 1
  for (int ti = 0; ti < ntl; ++ti){
    // issue next tile's stage first; it flies during this tile's compute
    STAGE((ti+1 < ntl) ? t0+ti+1 : t0, cur^1);

    const short8v* bb = &Bbuf[cur][0][0];
    const float2 cwv = cwsh[ti*32 + cl];

    f32x16 a0 = {}, a1 = {};
    __builtin_amdgcn_s_setprio(1);
    #pragma unroll
    for (int f=0; f<4; ++f){
      short8v bh = bb[f*64 + l];
      short8v bl = bb[(4+f)*64 + l];
      a0 = MFMA(ah[0][f], bh, a0);
      a1 = MFMA(ah[1][f], bh, a1);
      a0 = MFMA(ah[0][f], bl, a0);
      a1 = MFMA(ah[1][f], bl, a1);
      a0 = MFMA(al[0][f], bh, a0);
      a1 = MFMA(al[1][f], bh, a1);
    }
    __builtin_amdgcn_s_setprio(0);

    // epilogue: racc += 2^(L2E*dot + cn) * w
    #pragma unroll
    for (int r=0;r<16;++r){
      racc0[r] = fmaf(__builtin_amdgcn_exp2f(fmaf(a0[r], L2E, cwv.x)), cwv.y, racc0[r]);
      racc1[r] = fmaf(__builtin_amdgcn_exp2f(fmaf(a1[r], L2E, cwv.x)), cwv.y, racc1[r]);
    }

    // next tile's 2 loads were issued ~full tile ago -> drain is free
    asm volatile("s_waitcnt vmcnt(0)" ::: "memory");
    __syncthreads();
    cur ^= 1;
  }
  #undef STAGE

  // ---- reduce over 32 col-lanes, fold 2^xn, one atomic per row ----
  #pragma unroll
  for (int rf=0; rf<2; rf++){
    #pragma unroll
    for (int r=0;r<16;r++){
      float v = rf ? racc1[r] : racc0[r];
      v += __shfl_xor(v, 1);
      v += __shfl_xor(v, 2);
      v += __shfl_xor(v, 4);
      v += __shfl_xor(v, 8);
      v += __shfl_xor(v, 16);
      const int rit = (r&3) + 8*(r>>2) + 4*h;
      const float xnv = __shfl(xn[rf], rit);
      if (cl == 0)
        atomicAdd(&out[rows0 + rf*32 + rit], v * __builtin_amdgcn_exp2f(xnv));
    }
  }
}

extern "C" void kernel_launch(void* const* d_in, const int* in_sizes, int n_in,
                              void* d_out, int out_size, void* d_ws, size_t ws_size,
                              hipStream_t stream) {
  const float* X = (const float*)d_in[0];   // [B,64]
  const float* C = (const float*)d_in[1];   // [G,64]
  const float* W = (const float*)d_in[2];   // [G]
  float* out = (float*)d_out;               // [B]
  const int B = in_sizes[0] / 64;
  const int G = in_sizes[2];

  u16* Chi = (u16*)d_ws;                         // 1 MB
  u16* Clo = Chi + (size_t)G*64;                 // 1 MB
  float2* cw = (float2*)(Clo + (size_t)G*64);    // 64 KB

  hipMemsetAsync(out, 0, (size_t)B*sizeof(float), stream);
  convert_C<<<(G*4)/256, 256, 0, stream>>>(C, W, Chi, Clo, cw, G);
  rbf_mfma<<<(B/256)*GP, 256, 0, stream>>>(X, Chi, Clo, cw, out);
}